// Round 2
// baseline (2986.361 us; speedup 1.0000x reference)
//
#include <hip/hip_runtime.h>
#include <hip/hip_bf16.h>

#define CDIM 128
#define NG 128

__device__ __forceinline__ void atomicMaxF(float* addr, float val){
  if (val >= 0.f) atomicMax((int*)addr, __float_as_int(val));
  else            atomicMin((unsigned int*)addr, __float_as_uint(val));
}

// ---------- copy node features (layer-0 input; don't mutate d_in) ----------
__global__ void k_convert(const float* __restrict__ xin, float* __restrict__ xout, int n){
  int i = blockIdx.x*blockDim.x + threadIdx.x;
  if (i < n) xout[i] = xin[i];
}

// ---------- init lmax to -inf ----------
__global__ void k_init_lmax(float* __restrict__ lmax, int n){
  int i = blockIdx.x*blockDim.x + threadIdx.x;
  if (i < n) lmax[i] = -INFINITY;
}

// ---------- xl = x@Wl + bl ; xr = x@Wr + br  (16 nodes / block, 128 threads) ----------
__global__ void k_node_transform(const float* __restrict__ x,
    const float* __restrict__ Wl, const float* __restrict__ bl,
    const float* __restrict__ Wr, const float* __restrict__ br,
    float* __restrict__ xl, float* __restrict__ xr, int N)
{
  __shared__ float xs[16][CDIM];
  int t = threadIdx.x;              // 0..127 = output channel
  int n0 = blockIdx.x * 16;
  int nn = min(16, N - n0);
  for (int i = 0; i < nn; i++) xs[i][t] = x[(n0+i)*CDIM + t];
  __syncthreads();
  float accl[16], accr[16];
  #pragma unroll
  for (int i = 0; i < 16; i++){ accl[i]=0.f; accr[i]=0.f; }
  for (int k = 0; k < CDIM; k++){
    float wl = Wl[k*CDIM + t];
    float wr = Wr[k*CDIM + t];
    #pragma unroll
    for (int i = 0; i < 16; i++){
      accl[i] = fmaf(xs[i][k], wl, accl[i]);
      accr[i] = fmaf(xs[i][k], wr, accr[i]);
    }
  }
  float bbl = bl[t], bbr = br[t];
  for (int i = 0; i < nn; i++){
    xl[(n0+i)*CDIM + t] = accl[i] + bbl;
    xr[(n0+i)*CDIM + t] = accr[i] + bbr;
  }
}

// ---------- edge pass 1: logits + atomic max (2 edges per 256-thread block iter) ----------
__global__ void k_edge_logits(const float* __restrict__ xl, const float* __restrict__ xr,
    const float* __restrict__ eattr, const float* __restrict__ lineW,
    const float* __restrict__ att,
    const int* __restrict__ src, const int* __restrict__ dst,
    float* __restrict__ logits, float* __restrict__ lmax, int E, int ed)
{
  __shared__ float lw[12*CDIM];
  __shared__ float sat[CDIM];
  __shared__ float sea[2][12];
  int t = threadIdx.x;              // 0..255
  for (int i = t; i < ed*CDIM; i += 256) lw[i] = lineW[i];
  if (t < CDIM) sat[t] = att[t];
  __syncthreads();
  int slot = t >> 7;                // which of the 2 edges
  int c = t & 127;                  // channel
  int h = c >> 4, d = c & 15;
  for (int e0 = blockIdx.x*2; e0 < E; e0 += gridDim.x*2){
    int e = e0 + slot;
    if (c < ed && e < E) sea[slot][c] = eattr[(size_t)e*ed + c];
    __syncthreads();
    if (e < E){
      int s = src[e], dd = dst[e];
      float em = 0.f;
      for (int k = 0; k < ed; k++) em = fmaf(sea[slot][k], lw[k*CDIM + c], em);
      float m = xl[s*CDIM + c] + xr[dd*CDIM + c] + em;
      m = (m >= 0.f) ? m : 0.2f*m;
      float v = m * sat[c];
      #pragma unroll
      for (int off = 8; off >= 1; off >>= 1) v += __shfl_xor(v, off, 16);
      if (d == 0){
        logits[e*8 + h] = v;
        atomicMaxF(&lmax[dd*8 + h], v);
      }
    }
    __syncthreads();
  }
}

// ---------- finalize lmax, zero denom + agg ----------
__global__ void k_finalize(float* __restrict__ lmax, float* __restrict__ denom,
                           float* __restrict__ agg, int N){
  int i = blockIdx.x*blockDim.x + threadIdx.x;
  if (i < N*CDIM) agg[i] = 0.f;
  if (i < N*8){
    if (lmax[i] < -3.0e38f) lmax[i] = 0.f;   // only -inf possible
    denom[i] = 0.f;
  }
}

// ---------- edge pass 2: ex, denom+=ex, agg += ex*xl[src] ----------
__global__ void k_edge_agg(const float* __restrict__ xl,
    const float* __restrict__ logits, const float* __restrict__ lmax,
    float* __restrict__ denom, float* __restrict__ agg,
    const int* __restrict__ src, const int* __restrict__ dst, int E)
{
  int t = threadIdx.x;
  int slot = t >> 7, c = t & 127, h = c >> 4, d = c & 15;
  for (int e0 = blockIdx.x*2; e0 < E; e0 += gridDim.x*2){
    int e = e0 + slot;
    if (e < E){
      int s = src[e], dd = dst[e];
      float ex = expf(logits[e*8 + h] - lmax[dd*8 + h]);
      if (d == 0) atomicAdd(&denom[dd*8 + h], ex);
      atomicAdd(&agg[dd*CDIM + c], ex * xl[s*CDIM + c]);
    }
  }
}

// ---------- node epilogue: h = agg/denom + bias; x = h + elu(h@resW + resb) ----------
__global__ void k_node_epilogue(const float* __restrict__ agg, const float* __restrict__ denom,
    const float* __restrict__ bias,
    const float* __restrict__ resW, const float* __restrict__ resb,
    float* __restrict__ xout, int N)
{
  __shared__ float hs[16][CDIM];
  int t = threadIdx.x;
  int n0 = blockIdx.x * 16;
  int nn = min(16, N - n0);
  float bb = bias[t];
  for (int i = 0; i < nn; i++){
    int n = n0 + i;
    float a  = agg[n*CDIM + t];
    float dn = denom[n*8 + (t >> 4)] + 1e-16f;
    hs[i][t] = a/dn + bb;
  }
  __syncthreads();
  float acc[16];
  #pragma unroll
  for (int i = 0; i < 16; i++) acc[i] = 0.f;
  for (int k = 0; k < CDIM; k++){
    float w = resW[k*CDIM + t];
    #pragma unroll
    for (int i = 0; i < 16; i++) acc[i] = fmaf(hs[i][k], w, acc[i]);
  }
  float rb = resb[t];
  for (int i = 0; i < nn; i++){
    float r = acc[i] + rb;
    float e = (r > 0.f) ? r : expm1f(r);
    xout[(n0+i)*CDIM + t] = hs[i][t] + e;
  }
}

// ---------- pooling: pool[batch[n]][off + c] += x[n][c] ----------
__global__ void k_pool(const float* __restrict__ x, const int* __restrict__ batch,
                       float* __restrict__ pool, int N, int off){
  int i = blockIdx.x*blockDim.x + threadIdx.x;
  if (i < N*CDIM){
    int n = i >> 7, c = i & 127;
    atomicAdd(&pool[batch[n]*256 + off + c], x[i]);
  }
}

// ---------- head: z = elu(pool@fc1W + fc1b); out = sigmoid(z@fc2W + fc2b) ----------
__global__ void k_head(const float* __restrict__ pool,
    const float* __restrict__ fc1W, const float* __restrict__ fc1b,
    const float* __restrict__ fc2W, const float* __restrict__ fc2b,
    float* __restrict__ out)
{
  __shared__ float ps[256];
  __shared__ float zs[CDIM];
  int g = blockIdx.x, t = threadIdx.x;  // 128 threads
  ps[t]       = pool[g*256 + t];
  ps[t + 128] = pool[g*256 + 128 + t];
  __syncthreads();
  float acc = 0.f;
  for (int k = 0; k < 256; k++) acc = fmaf(ps[k], fc1W[k*CDIM + t], acc);
  acc += fc1b[t];
  float z = (acc > 0.f) ? acc : expm1f(acc);
  zs[t] = z * fc2W[t];
  __syncthreads();
  for (int s = 64; s > 0; s >>= 1){
    if (t < s) zs[t] += zs[t + s];
    __syncthreads();
  }
  if (t == 0){
    float o = zs[0] + fc2b[0];
    out[g] = 1.f / (1.f + expf(-o));
  }
}

extern "C" void kernel_launch(void* const* d_in, const int* in_sizes, int n_in,
                              void* d_out, int out_size, void* d_ws, size_t ws_size,
                              hipStream_t stream)
{
  const int NM = in_sizes[0] / CDIM, NP = in_sizes[1] / CDIM;
  const int EM = in_sizes[26] / 2,   EP = in_sizes[27] / 2;
  const int edM = in_sizes[2] / EM,  edP = in_sizes[3] / EP;

  const size_t NMAX = (size_t)((NM > NP) ? NM : NP);
  const size_t EMAX = (size_t)((EM > EP) ? EM : EP);

  float* W = (float*)d_ws;
  float* x      = W;
  float* xl     = W + NMAX*CDIM;
  float* xr     = W + 2*NMAX*CDIM;   // aliased with agg (xr dead after edge pass 1)
  float* agg    = xr;
  float* logits = W + 3*NMAX*CDIM;
  float* lmax   = logits + EMAX*8;
  float* denom  = lmax + NMAX*8;
  float* pool   = denom + NMAX*8;
  size_t needed = (3*NMAX*CDIM + EMAX*8 + 2*NMAX*8 + (size_t)NG*256) * sizeof(float);
  if (ws_size < needed) return;  // workspace insufficient — fail cleanly

  hipMemsetAsync(pool, 0, (size_t)NG*256*sizeof(float), stream);

  for (int sIdx = 0; sIdx < 2; sIdx++){
    const int base = sIdx ? 13 : 4;
    const float* linlW = (const float*)d_in[base+0];
    const float* linlb = (const float*)d_in[base+1];
    const float* linrW = (const float*)d_in[base+2];
    const float* linrb = (const float*)d_in[base+3];
    const float* lineW = (const float*)d_in[base+4];
    const float* att   = (const float*)d_in[base+5];
    const float* bias  = (const float*)d_in[base+6];
    const float* resW  = (const float*)d_in[base+7];
    const float* resb  = (const float*)d_in[base+8];

    const int N  = sIdx ? NP : NM;
    const int E  = sIdx ? EP : EM;
    const int ed = sIdx ? edP : edM;
    const float* xin   = (const float*)d_in[sIdx ? 1 : 0];
    const float* eattr = (const float*)d_in[sIdx ? 3 : 2];
    const int* ei    = (const int*)d_in[sIdx ? 27 : 26];
    const int* batch = (const int*)d_in[sIdx ? 29 : 28];
    const int* srcI  = ei;
    const int* dstI  = ei + E;

    k_convert<<<(N*CDIM + 255)/256, 256, 0, stream>>>(xin, x, N*CDIM);

    const int nodeBlocks = (N + 15)/16;
    const int flatBlocks = (N*CDIM + 255)/256;
    const int edgeBlocks = 8192;

    for (int l = 0; l < 3; l++){
      const float* Wl = linlW + (size_t)l*CDIM*CDIM;
      const float* bl = linlb + (size_t)l*CDIM;
      const float* Wr = linrW + (size_t)l*CDIM*CDIM;
      const float* br = linrb + (size_t)l*CDIM;
      const float* We = lineW + (size_t)l*ed*CDIM;
      const float* at = att   + (size_t)l*CDIM;
      const float* bi = bias  + (size_t)l*CDIM;
      const float* Rw = resW  + (size_t)l*CDIM*CDIM;
      const float* Rb = resb  + (size_t)l*CDIM;

      k_init_lmax<<<(N*8 + 255)/256, 256, 0, stream>>>(lmax, N*8);
      k_node_transform<<<nodeBlocks, 128, 0, stream>>>(x, Wl, bl, Wr, br, xl, xr, N);
      k_edge_logits<<<edgeBlocks, 256, 0, stream>>>(xl, xr, eattr, We, at, srcI, dstI,
                                                    logits, lmax, E, ed);
      k_finalize<<<flatBlocks, 256, 0, stream>>>(lmax, denom, agg, N);
      k_edge_agg<<<edgeBlocks, 256, 0, stream>>>(xl, logits, lmax, denom, agg, srcI, dstI, E);
      k_node_epilogue<<<nodeBlocks, 128, 0, stream>>>(agg, denom, bi, Rw, Rb, x, N);
    }

    k_pool<<<flatBlocks, 256, 0, stream>>>(x, batch, pool, N, sIdx ? 128 : 0);
  }

  const float* fc1W = (const float*)d_in[22];
  const float* fc1b = (const float*)d_in[23];
  const float* fc2W = (const float*)d_in[24];
  const float* fc2b = (const float*)d_in[25];
  k_head<<<NG, 128, 0, stream>>>(pool, fc1W, fc1b, fc2W, fc2b, (float*)d_out);
}

// Round 3
// 1813.984 us; speedup vs baseline: 1.6463x; 1.6463x over previous
//
#include <hip/hip_runtime.h>
#include <hip/hip_bf16.h>

#define CDIM 128
#define NG 128

// ---------- CSR build ----------
__global__ void k_count(const int* __restrict__ dst, int* __restrict__ deg, int E){
  int e = blockIdx.x*blockDim.x + threadIdx.x;
  if (e < E) atomicAdd(&deg[dst[e]], 1);
}

// single-block exclusive scan over deg -> rowptr, cursor
__global__ void k_scan(const int* __restrict__ deg, int* __restrict__ rowptr,
                       int* __restrict__ cursor, int N){
  __shared__ int tmp[1024];
  __shared__ int carry;
  int t = threadIdx.x;
  if (t == 0) carry = 0;
  __syncthreads();
  for (int base = 0; base < N; base += 1024){
    int i = base + t;
    int v = (i < N) ? deg[i] : 0;
    tmp[t] = v; __syncthreads();
    for (int off = 1; off < 1024; off <<= 1){
      int a = (t >= off) ? tmp[t-off] : 0;
      __syncthreads();
      tmp[t] += a;
      __syncthreads();
    }
    int excl = carry + tmp[t] - v;
    if (i < N){ rowptr[i] = excl; cursor[i] = excl; }
    int total = tmp[1023];
    __syncthreads();
    if (t == 0) carry += total;
    __syncthreads();
  }
  if (t == 0) rowptr[N] = carry;
}

__global__ void k_scatter(const int* __restrict__ src, const int* __restrict__ dst,
                          int* __restrict__ cursor, int* __restrict__ csr_src,
                          int* __restrict__ csr_eid, int E){
  int e = blockIdx.x*blockDim.x + threadIdx.x;
  if (e < E){
    int pos = atomicAdd(&cursor[dst[e]], 1);
    csr_src[pos] = src[e];
    csr_eid[pos] = e;
  }
}

// ---------- xl = x@Wl + bl ; xr = x@Wr + br  (16 nodes / block, 128 threads) ----------
__global__ void k_node_transform(const float* __restrict__ x,
    const float* __restrict__ Wl, const float* __restrict__ bl,
    const float* __restrict__ Wr, const float* __restrict__ br,
    float* __restrict__ xl, float* __restrict__ xr, int N)
{
  __shared__ float xs[16][CDIM];
  int t = threadIdx.x;              // output channel
  int n0 = blockIdx.x * 16;
  int nn = min(16, N - n0);
  for (int i = 0; i < nn; i++) xs[i][t] = x[(size_t)(n0+i)*CDIM + t];
  __syncthreads();
  float accl[16], accr[16];
  #pragma unroll
  for (int i = 0; i < 16; i++){ accl[i]=0.f; accr[i]=0.f; }
  for (int k = 0; k < CDIM; k++){
    float wl = Wl[k*CDIM + t];
    float wr = Wr[k*CDIM + t];
    #pragma unroll
    for (int i = 0; i < 16; i++){
      accl[i] = fmaf(xs[i][k], wl, accl[i]);
      accr[i] = fmaf(xs[i][k], wr, accr[i]);
    }
  }
  float bbl = bl[t], bbr = br[t];
  for (int i = 0; i < nn; i++){
    xl[(size_t)(n0+i)*CDIM + t] = accl[i] + bbl;
    xr[(size_t)(n0+i)*CDIM + t] = accr[i] + bbr;
  }
}

// ---------- fused per-dst GATv2: logits + online softmax + weighted agg ----------
// One 128-thread block per node. hout aliases xr (xr[n] only read by node n's block).
__global__ void k_gat_agg(const float* __restrict__ xl, const float* __restrict__ xr,
    const float* __restrict__ eattr, const float* __restrict__ lineW,
    const float* __restrict__ att, const float* __restrict__ bias,
    const int* __restrict__ rowptr, const int* __restrict__ deg,
    const int* __restrict__ csr_src, const int* __restrict__ csr_eid,
    float* __restrict__ hout, int N, int ed)
{
  __shared__ float lw[12*CDIM];
  __shared__ float satv[CDIM];
  int t = threadIdx.x;              // channel 0..127
  for (int i = t; i < ed*CDIM; i += 128) lw[i] = lineW[i];
  satv[t] = att[t];
  __syncthreads();
  float bb = bias[t];
  for (int n = blockIdx.x; n < N; n += gridDim.x){
    float xrv = xr[(size_t)n*CDIM + t];
    int start = rowptr[n], dg = deg[n];
    float m = -INFINITY, den = 0.f, acc = 0.f;
    for (int j = 0; j < dg; j++){
      int s = csr_src[start+j];
      int e = csr_eid[start+j];
      float xlv = xl[(size_t)s*CDIM + t];
      float em = 0.f;
      for (int k = 0; k < ed; k++) em = fmaf(eattr[(size_t)e*ed + k], lw[k*CDIM + t], em);
      float mm = xlv + xrv + em;
      mm = (mm >= 0.f) ? mm : 0.2f*mm;
      float v = mm * satv[t];
      #pragma unroll
      for (int off = 8; off >= 1; off >>= 1) v += __shfl_xor(v, off, 16);
      // v = logit for this lane's head (uniform across the 16 lanes of the head)
      if (v > m){
        float sc = __expf(m - v);   // m=-inf -> sc=0 on first edge
        den *= sc; acc *= sc; m = v;
      }
      float w = __expf(v - m);
      den += w;
      acc = fmaf(w, xlv, acc);
    }
    hout[(size_t)n*CDIM + t] = acc/(den + 1e-16f) + bb;
  }
}

// ---------- node epilogue: x = h + elu(h@resW + resb) ----------
__global__ void k_node_epilogue(const float* __restrict__ hin,
    const float* __restrict__ resW, const float* __restrict__ resb,
    float* __restrict__ xout, int N)
{
  __shared__ float hs[16][CDIM];
  int t = threadIdx.x;
  int n0 = blockIdx.x * 16;
  int nn = min(16, N - n0);
  for (int i = 0; i < nn; i++) hs[i][t] = hin[(size_t)(n0+i)*CDIM + t];
  __syncthreads();
  float acc[16];
  #pragma unroll
  for (int i = 0; i < 16; i++) acc[i] = 0.f;
  for (int k = 0; k < CDIM; k++){
    float w = resW[k*CDIM + t];
    #pragma unroll
    for (int i = 0; i < 16; i++) acc[i] = fmaf(hs[i][k], w, acc[i]);
  }
  float rb = resb[t];
  for (int i = 0; i < nn; i++){
    float r = acc[i] + rb;
    float e = (r > 0.f) ? r : expm1f(r);
    xout[(size_t)(n0+i)*CDIM + t] = hs[i][t] + e;
  }
}

// ---------- pooling ----------
__global__ void k_pool(const float* __restrict__ x, const int* __restrict__ batch,
                       float* __restrict__ pool, int N, int off){
  int i = blockIdx.x*blockDim.x + threadIdx.x;
  if (i < N*CDIM){
    int n = i >> 7, c = i & 127;
    atomicAdd(&pool[batch[n]*256 + off + c], x[i]);
  }
}

// ---------- head ----------
__global__ void k_head(const float* __restrict__ pool,
    const float* __restrict__ fc1W, const float* __restrict__ fc1b,
    const float* __restrict__ fc2W, const float* __restrict__ fc2b,
    float* __restrict__ out)
{
  __shared__ float ps[256];
  __shared__ float zs[CDIM];
  int g = blockIdx.x, t = threadIdx.x;  // 128 threads
  ps[t]       = pool[g*256 + t];
  ps[t + 128] = pool[g*256 + 128 + t];
  __syncthreads();
  float acc = 0.f;
  for (int k = 0; k < 256; k++) acc = fmaf(ps[k], fc1W[k*CDIM + t], acc);
  acc += fc1b[t];
  float z = (acc > 0.f) ? acc : expm1f(acc);
  zs[t] = z * fc2W[t];
  __syncthreads();
  for (int s = 64; s > 0; s >>= 1){
    if (t < s) zs[t] += zs[t + s];
    __syncthreads();
  }
  if (t == 0){
    float o = zs[0] + fc2b[0];
    out[g] = 1.f / (1.f + expf(-o));
  }
}

extern "C" void kernel_launch(void* const* d_in, const int* in_sizes, int n_in,
                              void* d_out, int out_size, void* d_ws, size_t ws_size,
                              hipStream_t stream)
{
  const int NM = in_sizes[0] / CDIM, NP = in_sizes[1] / CDIM;
  const int EM = in_sizes[26] / 2,   EP = in_sizes[27] / 2;
  const int edM = in_sizes[2] / EM,  edP = in_sizes[3] / EP;

  const size_t NMAX = (size_t)((NM > NP) ? NM : NP);
  const size_t EMAX = (size_t)((EM > EP) ? EM : EP);

  float* W = (float*)d_ws;
  float* x    = W;                         // NMAX*128
  float* xl   = x  + NMAX*CDIM;
  float* xr   = xl + NMAX*CDIM;            // hout aliases xr
  float* pool = xr + NMAX*CDIM;            // NG*256
  int* rowptr  = (int*)(pool + (size_t)NG*256);   // NMAX+1
  int* deg     = rowptr + NMAX + 1;
  int* cursor  = deg + NMAX;
  int* csr_src = cursor + NMAX;            // EMAX
  int* csr_eid = csr_src + EMAX;           // EMAX
  size_t needed = (3*NMAX*CDIM + (size_t)NG*256)*4 + (3*NMAX + 1 + 2*EMAX)*4;
  if (ws_size < needed) return;

  hipMemsetAsync(pool, 0, (size_t)NG*256*sizeof(float), stream);

  for (int sIdx = 0; sIdx < 2; sIdx++){
    const int base = sIdx ? 13 : 4;
    const float* linlW = (const float*)d_in[base+0];
    const float* linlb = (const float*)d_in[base+1];
    const float* linrW = (const float*)d_in[base+2];
    const float* linrb = (const float*)d_in[base+3];
    const float* lineW = (const float*)d_in[base+4];
    const float* att   = (const float*)d_in[base+5];
    const float* bias  = (const float*)d_in[base+6];
    const float* resW  = (const float*)d_in[base+7];
    const float* resb  = (const float*)d_in[base+8];

    const int N  = sIdx ? NP : NM;
    const int E  = sIdx ? EP : EM;
    const int ed = sIdx ? edP : edM;
    const float* xin   = (const float*)d_in[sIdx ? 1 : 0];
    const float* eattr = (const float*)d_in[sIdx ? 3 : 2];
    const int* ei    = (const int*)d_in[sIdx ? 27 : 26];
    const int* batch = (const int*)d_in[sIdx ? 29 : 28];
    const int* srcI  = ei;
    const int* dstI  = ei + E;

    // ---- CSR build (once per stack, reused for 3 layers) ----
    hipMemsetAsync(deg, 0, (size_t)N*sizeof(int), stream);
    k_count<<<(E + 255)/256, 256, 0, stream>>>(dstI, deg, E);
    k_scan<<<1, 1024, 0, stream>>>(deg, rowptr, cursor, N);
    k_scatter<<<(E + 255)/256, 256, 0, stream>>>(srcI, dstI, cursor, csr_src, csr_eid, E);

    const int nodeBlocks = (N + 15)/16;
    const int flatBlocks = (N*CDIM + 255)/256;

    for (int l = 0; l < 3; l++){
      const float* Wl = linlW + (size_t)l*CDIM*CDIM;
      const float* bl = linlb + (size_t)l*CDIM;
      const float* Wr = linrW + (size_t)l*CDIM*CDIM;
      const float* br = linrb + (size_t)l*CDIM;
      const float* We = lineW + (size_t)l*ed*CDIM;
      const float* at = att   + (size_t)l*CDIM;
      const float* bi = bias  + (size_t)l*CDIM;
      const float* Rw = resW  + (size_t)l*CDIM*CDIM;
      const float* Rb = resb  + (size_t)l*CDIM;

      k_node_transform<<<nodeBlocks, 128, 0, stream>>>(l == 0 ? xin : x,
                                                       Wl, bl, Wr, br, xl, xr, N);
      k_gat_agg<<<N, 128, 0, stream>>>(xl, xr, eattr, We, at, bi,
                                       rowptr, deg, csr_src, csr_eid, xr /*hout*/, N, ed);
      k_node_epilogue<<<nodeBlocks, 128, 0, stream>>>(xr, Rw, Rb, x, N);
    }

    k_pool<<<flatBlocks, 256, 0, stream>>>(x, batch, pool, N, sIdx ? 128 : 0);
  }

  const float* fc1W = (const float*)d_in[22];
  const float* fc1b = (const float*)d_in[23];
  const float* fc2W = (const float*)d_in[24];
  const float* fc2b = (const float*)d_in[25];
  k_head<<<NG, 128, 0, stream>>>(pool, fc1W, fc1b, fc2W, fc2b, (float*)d_out);
}

// Round 4
// 1475.377 us; speedup vs baseline: 2.0241x; 1.2295x over previous
//
#include <hip/hip_runtime.h>
#include <hip/hip_bf16.h>

#define CDIM 128
#define NG 128

// ---------- CSR build ----------
__global__ void k_count(const int* __restrict__ dst, int* __restrict__ deg, int E){
  int e = blockIdx.x*blockDim.x + threadIdx.x;
  if (e < E) atomicAdd(&deg[dst[e]], 1);
}

// single-block exclusive scan over deg -> rowptr, cursor
__global__ void k_scan(const int* __restrict__ deg, int* __restrict__ rowptr,
                       int* __restrict__ cursor, int N){
  __shared__ int tmp[1024];
  __shared__ int carry;
  int t = threadIdx.x;
  if (t == 0) carry = 0;
  __syncthreads();
  for (int base = 0; base < N; base += 1024){
    int i = base + t;
    int v = (i < N) ? deg[i] : 0;
    tmp[t] = v; __syncthreads();
    for (int off = 1; off < 1024; off <<= 1){
      int a = (t >= off) ? tmp[t-off] : 0;
      __syncthreads();
      tmp[t] += a;
      __syncthreads();
    }
    int excl = carry + tmp[t] - v;
    if (i < N){ rowptr[i] = excl; cursor[i] = excl; }
    int total = tmp[1023];
    __syncthreads();
    if (t == 0) carry += total;
    __syncthreads();
  }
  if (t == 0) rowptr[N] = carry;
}

__global__ void k_scatter(const int* __restrict__ src, const int* __restrict__ dst,
                          int* __restrict__ cursor, int* __restrict__ csr_src,
                          int* __restrict__ csr_eid, int E){
  int e = blockIdx.x*blockDim.x + threadIdx.x;
  if (e < E){
    int pos = atomicAdd(&cursor[dst[e]], 1);
    csr_src[pos] = src[e];
    csr_eid[pos] = e;
  }
}

// ---------- reorder eattr into CSR edge order (linear reads in gat kernel) ----------
__global__ void k_reorder_ea(const float* __restrict__ eattr, const int* __restrict__ eid,
                             float* __restrict__ ea_csr, int E, int ed){
  int i = blockIdx.x*blockDim.x + threadIdx.x;
  if (i < E*ed){
    int j = i / ed, k = i - j*ed;
    ea_csr[i] = eattr[(size_t)eid[j]*ed + k];
  }
}

// ---------- xl = x@Wl + bl ; xr = x@Wr + br  (16 nodes / block, 128 threads) ----------
__global__ void k_node_transform(const float* __restrict__ x,
    const float* __restrict__ Wl, const float* __restrict__ bl,
    const float* __restrict__ Wr, const float* __restrict__ br,
    float* __restrict__ xl, float* __restrict__ xr, int N)
{
  __shared__ float xs[16][CDIM];
  int t = threadIdx.x;              // output channel
  int n0 = blockIdx.x * 16;
  int nn = min(16, N - n0);
  for (int i = 0; i < nn; i++) xs[i][t] = x[(size_t)(n0+i)*CDIM + t];
  __syncthreads();
  float accl[16], accr[16];
  #pragma unroll
  for (int i = 0; i < 16; i++){ accl[i]=0.f; accr[i]=0.f; }
  for (int k = 0; k < CDIM; k++){
    float wl = Wl[k*CDIM + t];
    float wr = Wr[k*CDIM + t];
    #pragma unroll
    for (int i = 0; i < 16; i++){
      accl[i] = fmaf(xs[i][k], wl, accl[i]);
      accr[i] = fmaf(xs[i][k], wr, accr[i]);
    }
  }
  float bbl = bl[t], bbr = br[t];
  for (int i = 0; i < nn; i++){
    xl[(size_t)(n0+i)*CDIM + t] = accl[i] + bbl;
    xr[(size_t)(n0+i)*CDIM + t] = accr[i] + bbr;
  }
}

// ---------- fused per-dst GATv2 v2: 1 wave/node, float2 lanes, 2-edge unroll ----------
// Lane t owns channels (2t, 2t+1). Head h = t>>3 (8 lanes/head).
template<int ED>
__global__ void k_gat_agg2(const float2* __restrict__ xl2, const float2* __restrict__ xr2,
    const float* __restrict__ ea, const int* __restrict__ eid,   // eid==null -> ea already CSR-ordered
    const float* __restrict__ lineW, const float* __restrict__ att, const float* __restrict__ bias,
    const int* __restrict__ rowptr, const int* __restrict__ csr_src,
    float2* __restrict__ hout2, int N, int ed_rt)
{
  const int ed = (ED > 0) ? ED : ed_rt;
  __shared__ float lw[12*CDIM];
  int tb = threadIdx.x;             // 0..255
  for (int i = tb; i < ed*CDIM; i += 256) lw[i] = lineW[i];
  __syncthreads();
  int w = tb >> 6;                  // wave 0..3 -> node slot
  int t = tb & 63;                  // lane
  const float2* lw2 = (const float2*)lw;
  float2 at2 = ((const float2*)att)[t];
  float2 bb2 = ((const float2*)bias)[t];
  for (int n = blockIdx.x*4 + w; n < N; n += gridDim.x*4){
    float2 xrv = xr2[(size_t)n*64 + t];
    int start = rowptr[n], end = rowptr[n+1];
    float m = -INFINITY, den = 0.f, a0 = 0.f, a1 = 0.f;
    int j = start;
    for (; j + 1 < end; j += 2){
      int s0 = csr_src[j], s1 = csr_src[j+1];
      int e0 = eid ? eid[j]   : j;
      int e1 = eid ? eid[j+1] : j+1;
      float2 x0 = xl2[(size_t)s0*64 + t];
      float2 x1 = xl2[(size_t)s1*64 + t];
      float em00=0.f, em01=0.f, em10=0.f, em11=0.f;
      #pragma unroll
      for (int k = 0; k < ed; k++){
        float2 lwv = lw2[k*64 + t];
        float a = ea[(size_t)e0*ed + k];
        float b = ea[(size_t)e1*ed + k];
        em00 = fmaf(a, lwv.x, em00);
        em01 = fmaf(a, lwv.y, em01);
        em10 = fmaf(b, lwv.x, em10);
        em11 = fmaf(b, lwv.y, em11);
      }
      float m00 = x0.x + xrv.x + em00; m00 = (m00>=0.f)?m00:0.2f*m00;
      float m01 = x0.y + xrv.y + em01; m01 = (m01>=0.f)?m01:0.2f*m01;
      float m10 = x1.x + xrv.x + em10; m10 = (m10>=0.f)?m10:0.2f*m10;
      float m11 = x1.y + xrv.y + em11; m11 = (m11>=0.f)?m11:0.2f*m11;
      float v0 = fmaf(m00, at2.x, m01*at2.y);
      float v1 = fmaf(m10, at2.x, m11*at2.y);
      #pragma unroll
      for (int off = 1; off < 8; off <<= 1){
        v0 += __shfl_xor(v0, off, 8);
        v1 += __shfl_xor(v1, off, 8);
      }
      float vmax = fmaxf(v0, v1);
      if (vmax > m){
        float sc = __expf(m - vmax);
        den *= sc; a0 *= sc; a1 *= sc; m = vmax;
      }
      float w0 = __expf(v0 - m), w1 = __expf(v1 - m);
      den += w0 + w1;
      a0 = fmaf(w0, x0.x, fmaf(w1, x1.x, a0));
      a1 = fmaf(w0, x0.y, fmaf(w1, x1.y, a1));
    }
    if (j < end){
      int s0 = csr_src[j];
      int e0 = eid ? eid[j] : j;
      float2 x0 = xl2[(size_t)s0*64 + t];
      float em00=0.f, em01=0.f;
      #pragma unroll
      for (int k = 0; k < ed; k++){
        float2 lwv = lw2[k*64 + t];
        float a = ea[(size_t)e0*ed + k];
        em00 = fmaf(a, lwv.x, em00);
        em01 = fmaf(a, lwv.y, em01);
      }
      float m00 = x0.x + xrv.x + em00; m00 = (m00>=0.f)?m00:0.2f*m00;
      float m01 = x0.y + xrv.y + em01; m01 = (m01>=0.f)?m01:0.2f*m01;
      float v0 = fmaf(m00, at2.x, m01*at2.y);
      #pragma unroll
      for (int off = 1; off < 8; off <<= 1) v0 += __shfl_xor(v0, off, 8);
      if (v0 > m){
        float sc = __expf(m - v0);
        den *= sc; a0 *= sc; a1 *= sc; m = v0;
      }
      float w0 = __expf(v0 - m);
      den += w0;
      a0 = fmaf(w0, x0.x, a0);
      a1 = fmaf(w0, x0.y, a1);
    }
    float inv = 1.f/(den + 1e-16f);
    hout2[(size_t)n*64 + t] = make_float2(fmaf(a0, inv, bb2.x), fmaf(a1, inv, bb2.y));
  }
}

// ---------- node epilogue: x = h + elu(h@resW + resb) ----------
__global__ void k_node_epilogue(const float* __restrict__ hin,
    const float* __restrict__ resW, const float* __restrict__ resb,
    float* __restrict__ xout, int N)
{
  __shared__ float hs[16][CDIM];
  int t = threadIdx.x;
  int n0 = blockIdx.x * 16;
  int nn = min(16, N - n0);
  for (int i = 0; i < nn; i++) hs[i][t] = hin[(size_t)(n0+i)*CDIM + t];
  __syncthreads();
  float acc[16];
  #pragma unroll
  for (int i = 0; i < 16; i++) acc[i] = 0.f;
  for (int k = 0; k < CDIM; k++){
    float w = resW[k*CDIM + t];
    #pragma unroll
    for (int i = 0; i < 16; i++) acc[i] = fmaf(hs[i][k], w, acc[i]);
  }
  float rb = resb[t];
  for (int i = 0; i < nn; i++){
    float r = acc[i] + rb;
    float e = (r > 0.f) ? r : expm1f(r);
    xout[(size_t)(n0+i)*CDIM + t] = hs[i][t] + e;
  }
}

// ---------- pooling ----------
__global__ void k_pool(const float* __restrict__ x, const int* __restrict__ batch,
                       float* __restrict__ pool, int N, int off){
  int i = blockIdx.x*blockDim.x + threadIdx.x;
  if (i < N*CDIM){
    int n = i >> 7, c = i & 127;
    atomicAdd(&pool[batch[n]*256 + off + c], x[i]);
  }
}

// ---------- head ----------
__global__ void k_head(const float* __restrict__ pool,
    const float* __restrict__ fc1W, const float* __restrict__ fc1b,
    const float* __restrict__ fc2W, const float* __restrict__ fc2b,
    float* __restrict__ out)
{
  __shared__ float ps[256];
  __shared__ float zs[CDIM];
  int g = blockIdx.x, t = threadIdx.x;  // 128 threads
  ps[t]       = pool[g*256 + t];
  ps[t + 128] = pool[g*256 + 128 + t];
  __syncthreads();
  float acc = 0.f;
  for (int k = 0; k < 256; k++) acc = fmaf(ps[k], fc1W[k*CDIM + t], acc);
  acc += fc1b[t];
  float z = (acc > 0.f) ? acc : expm1f(acc);
  zs[t] = z * fc2W[t];
  __syncthreads();
  for (int s = 64; s > 0; s >>= 1){
    if (t < s) zs[t] += zs[t + s];
    __syncthreads();
  }
  if (t == 0){
    float o = zs[0] + fc2b[0];
    out[g] = 1.f / (1.f + expf(-o));
  }
}

extern "C" void kernel_launch(void* const* d_in, const int* in_sizes, int n_in,
                              void* d_out, int out_size, void* d_ws, size_t ws_size,
                              hipStream_t stream)
{
  const int NM = in_sizes[0] / CDIM, NP = in_sizes[1] / CDIM;
  const int EM = in_sizes[26] / 2,   EP = in_sizes[27] / 2;
  const int edM = in_sizes[2] / EM,  edP = in_sizes[3] / EP;

  const size_t NMAX = (size_t)((NM > NP) ? NM : NP);
  const size_t EMAX = (size_t)((EM > EP) ? EM : EP);
  const size_t EDMAX = (size_t)((edM > edP) ? edM : edP);

  float* W = (float*)d_ws;
  float* x    = W;                         // NMAX*128
  float* xl   = x  + NMAX*CDIM;
  float* xr   = xl + NMAX*CDIM;            // hout aliases xr
  float* pool = xr + NMAX*CDIM;            // NG*256
  int* rowptr  = (int*)(pool + (size_t)NG*256);   // NMAX+1
  int* deg     = rowptr + NMAX + 1;
  int* cursor  = deg + NMAX;
  int* csr_src = cursor + NMAX;            // EMAX
  int* csr_eid = csr_src + EMAX;           // EMAX
  float* ea_csr = (float*)(csr_eid + EMAX);  // EMAX*EDMAX (optional)

  size_t base_need = (3*NMAX*CDIM + (size_t)NG*256)*4 + (3*NMAX + 1 + 2*EMAX)*4;
  if (ws_size < base_need) return;
  const bool reorder = (ws_size >= base_need + EMAX*EDMAX*4);

  hipMemsetAsync(pool, 0, (size_t)NG*256*sizeof(float), stream);

  for (int sIdx = 0; sIdx < 2; sIdx++){
    const int base = sIdx ? 13 : 4;
    const float* linlW = (const float*)d_in[base+0];
    const float* linlb = (const float*)d_in[base+1];
    const float* linrW = (const float*)d_in[base+2];
    const float* linrb = (const float*)d_in[base+3];
    const float* lineW = (const float*)d_in[base+4];
    const float* att   = (const float*)d_in[base+5];
    const float* bias  = (const float*)d_in[base+6];
    const float* resW  = (const float*)d_in[base+7];
    const float* resb  = (const float*)d_in[base+8];

    const int N  = sIdx ? NP : NM;
    const int E  = sIdx ? EP : EM;
    const int ed = sIdx ? edP : edM;
    const float* xin   = (const float*)d_in[sIdx ? 1 : 0];
    const float* eattr = (const float*)d_in[sIdx ? 3 : 2];
    const int* ei    = (const int*)d_in[sIdx ? 27 : 26];
    const int* batch = (const int*)d_in[sIdx ? 29 : 28];
    const int* srcI  = ei;
    const int* dstI  = ei + E;

    // ---- CSR build (once per stack, reused for 3 layers) ----
    hipMemsetAsync(deg, 0, (size_t)N*sizeof(int), stream);
    k_count<<<(E + 255)/256, 256, 0, stream>>>(dstI, deg, E);
    k_scan<<<1, 1024, 0, stream>>>(deg, rowptr, cursor, N);
    k_scatter<<<(E + 255)/256, 256, 0, stream>>>(srcI, dstI, cursor, csr_src, csr_eid, E);

    const float* ea_use = eattr;
    const int* eid_use  = csr_eid;
    if (reorder){
      k_reorder_ea<<<(E*ed + 255)/256, 256, 0, stream>>>(eattr, csr_eid, ea_csr, E, ed);
      ea_use = ea_csr;
      eid_use = nullptr;
    }

    const int nodeBlocks = (N + 15)/16;
    const int flatBlocks = (N*CDIM + 255)/256;
    const int gatBlocks  = (N + 3)/4;

    for (int l = 0; l < 3; l++){
      const float* Wl = linlW + (size_t)l*CDIM*CDIM;
      const float* bl = linlb + (size_t)l*CDIM;
      const float* Wr = linrW + (size_t)l*CDIM*CDIM;
      const float* br = linrb + (size_t)l*CDIM;
      const float* We = lineW + (size_t)l*ed*CDIM;
      const float* at = att   + (size_t)l*CDIM;
      const float* bi = bias  + (size_t)l*CDIM;
      const float* Rw = resW  + (size_t)l*CDIM*CDIM;
      const float* Rb = resb  + (size_t)l*CDIM;

      k_node_transform<<<nodeBlocks, 128, 0, stream>>>(l == 0 ? xin : x,
                                                       Wl, bl, Wr, br, xl, xr, N);
      if (ed == 8)
        k_gat_agg2<8><<<gatBlocks, 256, 0, stream>>>((const float2*)xl, (const float2*)xr,
            ea_use, eid_use, We, at, bi, rowptr, csr_src, (float2*)xr, N, ed);
      else if (ed == 12)
        k_gat_agg2<12><<<gatBlocks, 256, 0, stream>>>((const float2*)xl, (const float2*)xr,
            ea_use, eid_use, We, at, bi, rowptr, csr_src, (float2*)xr, N, ed);
      else
        k_gat_agg2<0><<<gatBlocks, 256, 0, stream>>>((const float2*)xl, (const float2*)xr,
            ea_use, eid_use, We, at, bi, rowptr, csr_src, (float2*)xr, N, ed);
      k_node_epilogue<<<nodeBlocks, 128, 0, stream>>>(xr, Rw, Rb, x, N);
    }

    k_pool<<<flatBlocks, 256, 0, stream>>>(x, batch, pool, N, sIdx ? 128 : 0);
  }

  const float* fc1W = (const float*)d_in[22];
  const float* fc1b = (const float*)d_in[23];
  const float* fc2W = (const float*)d_in[24];
  const float* fc2b = (const float*)d_in[25];
  k_head<<<NG, 128, 0, stream>>>(pool, fc1W, fc1b, fc2W, fc2b, (float*)d_out);
}

// Round 5
// 1225.381 us; speedup vs baseline: 2.4371x; 1.2040x over previous
//
#include <hip/hip_runtime.h>
#include <hip/hip_bf16.h>

#define CDIM 128
#define NG 128

// ---------- CSR build ----------
__global__ void k_count(const int* __restrict__ dst, int* __restrict__ deg, int E){
  int e = blockIdx.x*blockDim.x + threadIdx.x;
  if (e < E) atomicAdd(&deg[dst[e]], 1);
}

// hierarchical scan: per-block local exclusive scan + block sums
__global__ void k_scan1(const int* __restrict__ deg, int* __restrict__ rowptr,
                        int* __restrict__ sums, int N){
  __shared__ int tmp[1024];
  int b = blockIdx.x, t = threadIdx.x;
  int i = b*1024 + t;
  int v = (i < N) ? deg[i] : 0;
  tmp[t] = v; __syncthreads();
  for (int off = 1; off < 1024; off <<= 1){
    int a = (t >= off) ? tmp[t-off] : 0;
    __syncthreads();
    tmp[t] += a;
    __syncthreads();
  }
  if (i < N) rowptr[i] = tmp[t] - v;     // local exclusive
  if (t == 1023) sums[b] = tmp[t];       // block total
}

// single block scan of block sums (chunked with carry)
__global__ void k_scan2(int* __restrict__ sums, int nb){
  __shared__ int tmp[1024];
  __shared__ int carry;
  int t = threadIdx.x;
  if (t == 0) carry = 0;
  __syncthreads();
  for (int base = 0; base < nb; base += 1024){
    int i = base + t;
    int v = (i < nb) ? sums[i] : 0;
    tmp[t] = v; __syncthreads();
    for (int off = 1; off < 1024; off <<= 1){
      int a = (t >= off) ? tmp[t-off] : 0;
      __syncthreads();
      tmp[t] += a;
      __syncthreads();
    }
    if (i < nb) sums[i] = carry + tmp[t] - v;   // exclusive
    int tot = tmp[1023];
    __syncthreads();
    if (t == 0) carry += tot;
    __syncthreads();
  }
  if (t == 0) sums[nb] = carry;          // grand total
}

__global__ void k_scan3(int* __restrict__ rowptr, int* __restrict__ cursor,
                        const int* __restrict__ sums, int N, int nb){
  int i = blockIdx.x*blockDim.x + threadIdx.x;
  if (i < N){
    int r = rowptr[i] + sums[i >> 10];
    rowptr[i] = r; cursor[i] = r;
  }
  if (i == 0) rowptr[N] = sums[nb];
}

__global__ void k_scatter(const int* __restrict__ src, const int* __restrict__ dst,
                          int* __restrict__ cursor, int* __restrict__ csr_src,
                          int* __restrict__ csr_eid, int E){
  int e = blockIdx.x*blockDim.x + threadIdx.x;
  if (e < E){
    int pos = atomicAdd(&cursor[dst[e]], 1);
    csr_src[pos] = src[e];
    csr_eid[pos] = e;
  }
}

// ---------- reorder eattr into CSR edge order ----------
__global__ void k_reorder_ea(const float* __restrict__ eattr, const int* __restrict__ eid,
                             float* __restrict__ ea_csr, int E, int ed){
  int i = blockIdx.x*blockDim.x + threadIdx.x;
  if (i < E*ed){
    int j = i / ed, k = i - j*ed;
    ea_csr[i] = eattr[(size_t)eid[j]*ed + k];
  }
}

// ---------- xl = x@Wl + bl ; xr = x@Wr + br ----------
__global__ void k_node_transform(const float* __restrict__ x,
    const float* __restrict__ Wl, const float* __restrict__ bl,
    const float* __restrict__ Wr, const float* __restrict__ br,
    float* __restrict__ xl, float* __restrict__ xr, int N)
{
  __shared__ float xs[16][CDIM];
  int t = threadIdx.x;
  int n0 = blockIdx.x * 16;
  int nn = min(16, N - n0);
  for (int i = 0; i < nn; i++) xs[i][t] = x[(size_t)(n0+i)*CDIM + t];
  __syncthreads();
  float accl[16], accr[16];
  #pragma unroll
  for (int i = 0; i < 16; i++){ accl[i]=0.f; accr[i]=0.f; }
  for (int k = 0; k < CDIM; k++){
    float wl = Wl[k*CDIM + t];
    float wr = Wr[k*CDIM + t];
    #pragma unroll
    for (int i = 0; i < 16; i++){
      accl[i] = fmaf(xs[i][k], wl, accl[i]);
      accr[i] = fmaf(xs[i][k], wr, accr[i]);
    }
  }
  float bbl = bl[t], bbr = br[t];
  for (int i = 0; i < nn; i++){
    xl[(size_t)(n0+i)*CDIM + t] = accl[i] + bbl;
    xr[(size_t)(n0+i)*CDIM + t] = accr[i] + bbr;
  }
}

// ---------- fused per-dst GATv2 v3: persistent waves, float2 lanes, 4-edge unroll ----------
template<int ED>
__global__ void k_gat_agg2(const float2* __restrict__ xl2, const float2* __restrict__ xr2,
    const float* __restrict__ ea, const int* __restrict__ eid,
    const float* __restrict__ lineW, const float* __restrict__ att, const float* __restrict__ bias,
    const int* __restrict__ rowptr, const int* __restrict__ csr_src,
    float2* __restrict__ hout2, int N, int ed_rt)
{
  const int ed = (ED > 0) ? ED : ed_rt;
  __shared__ float lw[12*CDIM];
  int tb = threadIdx.x;
  for (int i = tb; i < ed*CDIM; i += 256) lw[i] = lineW[i];
  __syncthreads();
  int w = tb >> 6;
  int t = tb & 63;
  const float2* lw2 = (const float2*)lw;
  float2 at2 = ((const float2*)att)[t];
  float2 bb2 = ((const float2*)bias)[t];
  for (int n = blockIdx.x*4 + w; n < N; n += gridDim.x*4){
    float2 xrv = xr2[(size_t)n*64 + t];
    int start = rowptr[n], end = rowptr[n+1];
    float m = -INFINITY, den = 0.f, a0 = 0.f, a1 = 0.f;
    int j = start;
    for (; j + 3 < end; j += 4){
      int s0 = csr_src[j],   s1 = csr_src[j+1];
      int s2 = csr_src[j+2], s3 = csr_src[j+3];
      int e0 = eid ? eid[j]   : j,   e1 = eid ? eid[j+1] : j+1;
      int e2 = eid ? eid[j+2] : j+2, e3 = eid ? eid[j+3] : j+3;
      float2 x0 = xl2[(size_t)s0*64 + t];
      float2 x1 = xl2[(size_t)s1*64 + t];
      float2 x2 = xl2[(size_t)s2*64 + t];
      float2 x3 = xl2[(size_t)s3*64 + t];
      float em00=0.f, em01=0.f, em10=0.f, em11=0.f;
      float em20=0.f, em21=0.f, em30=0.f, em31=0.f;
      #pragma unroll
      for (int k = 0; k < ed; k++){
        float2 lwv = lw2[k*64 + t];
        float a = ea[(size_t)e0*ed + k];
        float b = ea[(size_t)e1*ed + k];
        float c = ea[(size_t)e2*ed + k];
        float d = ea[(size_t)e3*ed + k];
        em00 = fmaf(a, lwv.x, em00); em01 = fmaf(a, lwv.y, em01);
        em10 = fmaf(b, lwv.x, em10); em11 = fmaf(b, lwv.y, em11);
        em20 = fmaf(c, lwv.x, em20); em21 = fmaf(c, lwv.y, em21);
        em30 = fmaf(d, lwv.x, em30); em31 = fmaf(d, lwv.y, em31);
      }
      float m00 = x0.x + xrv.x + em00; m00 = (m00>=0.f)?m00:0.2f*m00;
      float m01 = x0.y + xrv.y + em01; m01 = (m01>=0.f)?m01:0.2f*m01;
      float m10 = x1.x + xrv.x + em10; m10 = (m10>=0.f)?m10:0.2f*m10;
      float m11 = x1.y + xrv.y + em11; m11 = (m11>=0.f)?m11:0.2f*m11;
      float m20 = x2.x + xrv.x + em20; m20 = (m20>=0.f)?m20:0.2f*m20;
      float m21 = x2.y + xrv.y + em21; m21 = (m21>=0.f)?m21:0.2f*m21;
      float m30 = x3.x + xrv.x + em30; m30 = (m30>=0.f)?m30:0.2f*m30;
      float m31 = x3.y + xrv.y + em31; m31 = (m31>=0.f)?m31:0.2f*m31;
      float v0 = fmaf(m00, at2.x, m01*at2.y);
      float v1 = fmaf(m10, at2.x, m11*at2.y);
      float v2 = fmaf(m20, at2.x, m21*at2.y);
      float v3 = fmaf(m30, at2.x, m31*at2.y);
      #pragma unroll
      for (int off = 1; off < 8; off <<= 1){
        v0 += __shfl_xor(v0, off, 8);
        v1 += __shfl_xor(v1, off, 8);
        v2 += __shfl_xor(v2, off, 8);
        v3 += __shfl_xor(v3, off, 8);
      }
      float vmax = fmaxf(fmaxf(v0, v1), fmaxf(v2, v3));
      if (vmax > m){
        float sc = __expf(m - vmax);
        den *= sc; a0 *= sc; a1 *= sc; m = vmax;
      }
      float w0 = __expf(v0 - m), w1 = __expf(v1 - m);
      float w2 = __expf(v2 - m), w3 = __expf(v3 - m);
      den += (w0 + w1) + (w2 + w3);
      a0 = fmaf(w0, x0.x, fmaf(w1, x1.x, fmaf(w2, x2.x, fmaf(w3, x3.x, a0))));
      a1 = fmaf(w0, x0.y, fmaf(w1, x1.y, fmaf(w2, x2.y, fmaf(w3, x3.y, a1))));
    }
    for (; j < end; j++){
      int s0 = csr_src[j];
      int e0 = eid ? eid[j] : j;
      float2 x0 = xl2[(size_t)s0*64 + t];
      float em00=0.f, em01=0.f;
      #pragma unroll
      for (int k = 0; k < ed; k++){
        float2 lwv = lw2[k*64 + t];
        float a = ea[(size_t)e0*ed + k];
        em00 = fmaf(a, lwv.x, em00);
        em01 = fmaf(a, lwv.y, em01);
      }
      float m00 = x0.x + xrv.x + em00; m00 = (m00>=0.f)?m00:0.2f*m00;
      float m01 = x0.y + xrv.y + em01; m01 = (m01>=0.f)?m01:0.2f*m01;
      float v0 = fmaf(m00, at2.x, m01*at2.y);
      #pragma unroll
      for (int off = 1; off < 8; off <<= 1) v0 += __shfl_xor(v0, off, 8);
      if (v0 > m){
        float sc = __expf(m - v0);
        den *= sc; a0 *= sc; a1 *= sc; m = v0;
      }
      float w0 = __expf(v0 - m);
      den += w0;
      a0 = fmaf(w0, x0.x, a0);
      a1 = fmaf(w0, x0.y, a1);
    }
    float inv = 1.f/(den + 1e-16f);
    hout2[(size_t)n*64 + t] = make_float2(fmaf(a0, inv, bb2.x), fmaf(a1, inv, bb2.y));
  }
}

// ---------- node epilogue: x = h + elu(h@resW + resb) ----------
__global__ void k_node_epilogue(const float* __restrict__ hin,
    const float* __restrict__ resW, const float* __restrict__ resb,
    float* __restrict__ xout, int N)
{
  __shared__ float hs[16][CDIM];
  int t = threadIdx.x;
  int n0 = blockIdx.x * 16;
  int nn = min(16, N - n0);
  for (int i = 0; i < nn; i++) hs[i][t] = hin[(size_t)(n0+i)*CDIM + t];
  __syncthreads();
  float acc[16];
  #pragma unroll
  for (int i = 0; i < 16; i++) acc[i] = 0.f;
  for (int k = 0; k < CDIM; k++){
    float w = resW[k*CDIM + t];
    #pragma unroll
    for (int i = 0; i < 16; i++) acc[i] = fmaf(hs[i][k], w, acc[i]);
  }
  float rb = resb[t];
  for (int i = 0; i < nn; i++){
    float r = acc[i] + rb;
    float e = (r > 0.f) ? r : expm1f(r);
    xout[(size_t)(n0+i)*CDIM + t] = hs[i][t] + e;
  }
}

// ---------- pooling ----------
__global__ void k_pool(const float* __restrict__ x, const int* __restrict__ batch,
                       float* __restrict__ pool, int N, int off){
  int i = blockIdx.x*blockDim.x + threadIdx.x;
  if (i < N*CDIM){
    int n = i >> 7, c = i & 127;
    atomicAdd(&pool[batch[n]*256 + off + c], x[i]);
  }
}

// ---------- head ----------
__global__ void k_head(const float* __restrict__ pool,
    const float* __restrict__ fc1W, const float* __restrict__ fc1b,
    const float* __restrict__ fc2W, const float* __restrict__ fc2b,
    float* __restrict__ out)
{
  __shared__ float ps[256];
  __shared__ float zs[CDIM];
  int g = blockIdx.x, t = threadIdx.x;
  ps[t]       = pool[g*256 + t];
  ps[t + 128] = pool[g*256 + 128 + t];
  __syncthreads();
  float acc = 0.f;
  for (int k = 0; k < 256; k++) acc = fmaf(ps[k], fc1W[k*CDIM + t], acc);
  acc += fc1b[t];
  float z = (acc > 0.f) ? acc : expm1f(acc);
  zs[t] = z * fc2W[t];
  __syncthreads();
  for (int s = 64; s > 0; s >>= 1){
    if (t < s) zs[t] += zs[t + s];
    __syncthreads();
  }
  if (t == 0){
    float o = zs[0] + fc2b[0];
    out[g] = 1.f / (1.f + expf(-o));
  }
}

extern "C" void kernel_launch(void* const* d_in, const int* in_sizes, int n_in,
                              void* d_out, int out_size, void* d_ws, size_t ws_size,
                              hipStream_t stream)
{
  const int NM = in_sizes[0] / CDIM, NP = in_sizes[1] / CDIM;
  const int EM = in_sizes[26] / 2,   EP = in_sizes[27] / 2;
  const int edM = in_sizes[2] / EM,  edP = in_sizes[3] / EP;

  const size_t NMAX = (size_t)((NM > NP) ? NM : NP);
  const size_t EMAX = (size_t)((EM > EP) ? EM : EP);
  const size_t EDMAX = (size_t)((edM > edP) ? edM : edP);
  const size_t NBMAX = (NMAX + 1023)/1024;

  float* W = (float*)d_ws;
  float* x    = W;
  float* xl   = x  + NMAX*CDIM;
  float* xr   = xl + NMAX*CDIM;            // hout aliases xr
  float* pool = xr + NMAX*CDIM;
  int* rowptr  = (int*)(pool + (size_t)NG*256);
  int* deg     = rowptr + NMAX + 1;
  int* cursor  = deg + NMAX;
  int* sums    = cursor + NMAX;            // NBMAX+1
  int* csr_src = sums + NBMAX + 1;
  int* csr_eid = csr_src + EMAX;
  float* ea_csr = (float*)(csr_eid + EMAX);

  size_t base_need = (3*NMAX*CDIM + (size_t)NG*256)*4
                   + (3*NMAX + 1 + NBMAX + 1 + 2*EMAX)*4;
  if (ws_size < base_need) return;
  const bool reorder = (ws_size >= base_need + EMAX*EDMAX*4);

  hipMemsetAsync(pool, 0, (size_t)NG*256*sizeof(float), stream);

  for (int sIdx = 0; sIdx < 2; sIdx++){
    const int base = sIdx ? 13 : 4;
    const float* linlW = (const float*)d_in[base+0];
    const float* linlb = (const float*)d_in[base+1];
    const float* linrW = (const float*)d_in[base+2];
    const float* linrb = (const float*)d_in[base+3];
    const float* lineW = (const float*)d_in[base+4];
    const float* att   = (const float*)d_in[base+5];
    const float* bias  = (const float*)d_in[base+6];
    const float* resW  = (const float*)d_in[base+7];
    const float* resb  = (const float*)d_in[base+8];

    const int N  = sIdx ? NP : NM;
    const int E  = sIdx ? EP : EM;
    const int ed = sIdx ? edP : edM;
    const float* xin   = (const float*)d_in[sIdx ? 1 : 0];
    const float* eattr = (const float*)d_in[sIdx ? 3 : 2];
    const int* ei    = (const int*)d_in[sIdx ? 27 : 26];
    const int* batch = (const int*)d_in[sIdx ? 29 : 28];
    const int* srcI  = ei;
    const int* dstI  = ei + E;

    // ---- CSR build ----
    const int nb = (N + 1023)/1024;
    hipMemsetAsync(deg, 0, (size_t)N*sizeof(int), stream);
    k_count<<<(E + 255)/256, 256, 0, stream>>>(dstI, deg, E);
    k_scan1<<<nb, 1024, 0, stream>>>(deg, rowptr, sums, N);
    k_scan2<<<1, 1024, 0, stream>>>(sums, nb);
    k_scan3<<<(N + 255)/256, 256, 0, stream>>>(rowptr, cursor, sums, N, nb);
    k_scatter<<<(E + 255)/256, 256, 0, stream>>>(srcI, dstI, cursor, csr_src, csr_eid, E);

    const float* ea_use = eattr;
    const int* eid_use  = csr_eid;
    if (reorder){
      k_reorder_ea<<<(E*ed + 255)/256, 256, 0, stream>>>(eattr, csr_eid, ea_csr, E, ed);
      ea_use = ea_csr;
      eid_use = nullptr;
    }

    const int nodeBlocks = (N + 15)/16;
    const int flatBlocks = (N*CDIM + 255)/256;
    int gatBlocks = (N + 3)/4;
    if (gatBlocks > 2048) gatBlocks = 2048;

    for (int l = 0; l < 3; l++){
      const float* Wl = linlW + (size_t)l*CDIM*CDIM;
      const float* bl = linlb + (size_t)l*CDIM;
      const float* Wr = linrW + (size_t)l*CDIM*CDIM;
      const float* br = linrb + (size_t)l*CDIM;
      const float* We = lineW + (size_t)l*ed*CDIM;
      const float* at = att   + (size_t)l*CDIM;
      const float* bi = bias  + (size_t)l*CDIM;
      const float* Rw = resW  + (size_t)l*CDIM*CDIM;
      const float* Rb = resb  + (size_t)l*CDIM;

      k_node_transform<<<nodeBlocks, 128, 0, stream>>>(l == 0 ? xin : x,
                                                       Wl, bl, Wr, br, xl, xr, N);
      if (ed == 8)
        k_gat_agg2<8><<<gatBlocks, 256, 0, stream>>>((const float2*)xl, (const float2*)xr,
            ea_use, eid_use, We, at, bi, rowptr, csr_src, (float2*)xr, N, ed);
      else if (ed == 12)
        k_gat_agg2<12><<<gatBlocks, 256, 0, stream>>>((const float2*)xl, (const float2*)xr,
            ea_use, eid_use, We, at, bi, rowptr, csr_src, (float2*)xr, N, ed);
      else
        k_gat_agg2<0><<<gatBlocks, 256, 0, stream>>>((const float2*)xl, (const float2*)xr,
            ea_use, eid_use, We, at, bi, rowptr, csr_src, (float2*)xr, N, ed);
      k_node_epilogue<<<nodeBlocks, 128, 0, stream>>>(xr, Rw, Rb, x, N);
    }

    k_pool<<<flatBlocks, 256, 0, stream>>>(x, batch, pool, N, sIdx ? 128 : 0);
  }

  const float* fc1W = (const float*)d_in[22];
  const float* fc1b = (const float*)d_in[23];
  const float* fc2W = (const float*)d_in[24];
  const float* fc2b = (const float*)d_in[25];
  k_head<<<NG, 128, 0, stream>>>(pool, fc1W, fc1b, fc2W, fc2b, (float*)d_out);
}